// Round 1
// baseline (3873.017 us; speedup 1.0000x reference)
//
#include <hip/hip_runtime.h>

#define B_SZ 16384
#define THRV 1.0f

// ---------------- layer 1 input current (computed once; input constant over time) ----
__global__ __launch_bounds__(256) void k_cur1(const float* __restrict__ x,
                                              const float* __restrict__ W1,
                                              const float* __restrict__ b1,
                                              float* __restrict__ cur1) {
    int id = blockIdx.x * 256 + threadIdx.x;   // B*256 threads
    int s = id >> 8, j = id & 255;
    const float* xr = x + s * 6;
    const float* wr = W1 + j * 6;
    float sum = 0.f;
#pragma unroll
    for (int i = 0; i < 6; ++i) sum = fmaf(xr[i], wr[i], sum);
    cur1[id] = sum + b1[j];
}

// ---------------- layer-1 LIF (no matmul: current is cur1 every step) ----------------
__global__ __launch_bounds__(256) void k_lif1(const float* __restrict__ cur1,
                                              float* __restrict__ m1,
                                              float* __restrict__ spk,
                                              int first) {
    int id = blockIdx.x * 256 + threadIdx.x;
    float c = cur1[id];
    float mp = first ? 0.f : m1[id];
    float mn = fmaf(0.9f, mp, c) - (mp > THRV ? THRV : 0.f);
    m1[id] = mn;
    spk[id] = (mn > THRV) ? 1.f : 0.f;
}

// ---------------- fused GEMM (spk_in @ W^T + b) + LIF update -------------------------
// NIN fixed = 256. Tile 64 samples x 64 out-neurons, 4x4 per thread, float2 LDS reads.
__global__ __launch_bounds__(256) void k_lif_mm(const float* __restrict__ spk_in, // [B][256]
                                                const float* __restrict__ W,      // [NOUT][256]
                                                const float* __restrict__ bias,   // [NOUT]
                                                float* __restrict__ m,            // [B][NOUT]
                                                float* __restrict__ spk_out,      // [B][NOUT]
                                                float beta, int first, int NOUT) {
    __shared__ float wl[64][66];
    __shared__ float sl[64][66];
    int tid = threadIdx.x;
    int s0 = blockIdx.x * 64;
    int j0 = blockIdx.y * 64;
    int jj = (tid & 15) * 4;
    int ss = (tid >> 4) * 4;
    float acc[4][4] = {};

    for (int i0 = 0; i0 < 256; i0 += 64) {
#pragma unroll
        for (int k = 0; k < 8; ++k) {
            int lin = tid + k * 256;            // 0..2047
            int row = lin >> 5, c2 = (lin & 31) * 2;
            *(float2*)&wl[row][c2] = *(const float2*)&W[(j0 + row) * 256 + i0 + c2];
            *(float2*)&sl[row][c2] = *(const float2*)&spk_in[(s0 + row) * 256 + i0 + c2];
        }
        __syncthreads();
#pragma unroll
        for (int i2 = 0; i2 < 32; ++i2) {
            float2 wv[4], sv[4];
#pragma unroll
            for (int q = 0; q < 4; ++q) wv[q] = *(const float2*)&wl[jj + q][i2 * 2];
#pragma unroll
            for (int p = 0; p < 4; ++p) sv[p] = *(const float2*)&sl[ss + p][i2 * 2];
#pragma unroll
            for (int q = 0; q < 4; ++q)
#pragma unroll
                for (int p = 0; p < 4; ++p) {
                    acc[q][p] = fmaf(wv[q].x, sv[p].x, acc[q][p]);
                    acc[q][p] = fmaf(wv[q].y, sv[p].y, acc[q][p]);
                }
        }
        __syncthreads();
    }

#pragma unroll
    for (int p = 0; p < 4; ++p) {
        int s = s0 + ss + p;
#pragma unroll
        for (int q = 0; q < 4; ++q) {
            int j = j0 + jj + q;
            int idx = s * NOUT + j;
            float cur = acc[q][p] + bias[j];
            float mp = first ? 0.f : m[idx];
            float mn = fmaf(beta, mp, cur) - (mp > THRV ? THRV : 0.f);
            m[idx] = mn;
            spk_out[idx] = (mn > THRV) ? 1.f : 0.f;
        }
    }
}

// ---------------- output layer: acc += spk5 @ W6^T + b6 ------------------------------
__global__ __launch_bounds__(256) void k_out(const float* __restrict__ spk5, // [B][128]
                                             const float* __restrict__ W6,   // [3][128]
                                             const float* __restrict__ b6,   // [3]
                                             float* __restrict__ acc,        // [B][3]
                                             int first) {
    __shared__ float w6l[3][128];
    int tid = threadIdx.x;
    if (tid < 384) ((float*)w6l)[tid] = W6[tid];
    __syncthreads();
    int s = blockIdx.x * 256 + tid;
    const float4* row = (const float4*)spk5 + (size_t)s * 32;
    float a[3] = {0.f, 0.f, 0.f};
#pragma unroll
    for (int i4 = 0; i4 < 32; ++i4) {
        float4 v = row[i4];
        int i = i4 * 4;
#pragma unroll
        for (int k = 0; k < 3; ++k) {
            a[k] = fmaf(v.x, w6l[k][i], a[k]);
            a[k] = fmaf(v.y, w6l[k][i + 1], a[k]);
            a[k] = fmaf(v.z, w6l[k][i + 2], a[k]);
            a[k] = fmaf(v.w, w6l[k][i + 3], a[k]);
        }
    }
    int o = s * 3;
#pragma unroll
    for (int k = 0; k < 3; ++k) {
        float ov = a[k] + b6[k];
        acc[o + k] = first ? ov : (acc[o + k] + ov);
    }
}

__global__ __launch_bounds__(256) void k_final(const float* __restrict__ acc,
                                               float* __restrict__ out) {
    int id = blockIdx.x * 256 + threadIdx.x;
    out[id] = acc[id] / 15.0f;
}

extern "C" void kernel_launch(void* const* d_in, const int* in_sizes, int n_in,
                              void* d_out, int out_size, void* d_ws, size_t ws_size,
                              hipStream_t stream) {
    const float* x  = (const float*)d_in[0];
    const float* W1 = (const float*)d_in[1];
    const float* b1 = (const float*)d_in[2];
    const float* W2 = (const float*)d_in[3];
    const float* b2 = (const float*)d_in[4];
    const float* W3 = (const float*)d_in[5];
    const float* b3 = (const float*)d_in[6];
    const float* W4 = (const float*)d_in[7];
    const float* b4 = (const float*)d_in[8];
    const float* W5 = (const float*)d_in[9];
    const float* b5 = (const float*)d_in[10];
    const float* W6 = (const float*)d_in[11];
    const float* b6 = (const float*)d_in[12];
    float* out = (float*)d_out;

    const size_t NB = (size_t)B_SZ * 256;
    float* ws   = (float*)d_ws;
    float* cur1 = ws;
    float* m1   = cur1 + NB;
    float* m2   = m1 + NB;
    float* m3   = m2 + NB;
    float* m4   = m3 + NB;
    float* m5   = m4 + NB;                         // B*128
    float* spkA = m5 + (size_t)B_SZ * 128;
    float* spkB = spkA + NB;
    float* acc  = spkB + NB;                       // B*3
    size_t need_bytes = (size_t)((acc + (size_t)B_SZ * 3) - ws) * sizeof(float);
    if (ws_size < need_bytes) return;              // insufficient scratch -> loud failure

    k_cur1<<<B_SZ, 256, 0, stream>>>(x, W1, b1, cur1);
    for (int t = 0; t < 15; ++t) {
        int first = (t == 0);
        k_lif1<<<B_SZ, 256, 0, stream>>>(cur1, m1, spkA, first);
        k_lif_mm<<<dim3(256, 4), 256, 0, stream>>>(spkA, W2, b2, m2, spkB, 0.88f, first, 256);
        k_lif_mm<<<dim3(256, 4), 256, 0, stream>>>(spkB, W3, b3, m3, spkA, 0.86f, first, 256);
        k_lif_mm<<<dim3(256, 4), 256, 0, stream>>>(spkA, W4, b4, m4, spkB, 0.84f, first, 256);
        k_lif_mm<<<dim3(256, 2), 256, 0, stream>>>(spkB, W5, b5, m5, spkA, 0.82f, first, 128);
        k_out<<<B_SZ / 256, 256, 0, stream>>>(spkA, W6, b6, acc, first);
    }
    k_final<<<(B_SZ * 3) / 256, 256, 0, stream>>>(acc, out);
}